// Round 20
// baseline (227.202 us; speedup 1.0000x reference)
//
#include <hip/hip_runtime.h>
#include <math.h>

// MoE: T=4096, D=1024, H=2048, O=1024, E=8, top-2.
// Routed sparse: 68.7 GFLOP bf16 MFMA. GEMMs: round-11 proven KTILE config
// (BM=192/BN=256/BK=64, 8 waves, 2 barrier-pairs/K-tile, counted per-wave
// vmcnt ring, setprio, chunk-XOR swizzle, LDS 112 KB). Front: gate + both
// transposes (v3 register micro-transpose) in one launch. This round:
// combine fused into gemm2 epilogue via deterministic 2-per-address
// commutative fp32 atomicAdd (y buffer + combine kernel removed).

#define T_TOK 4096
#define DIM   1024
#define HID   2048
#define OUTD  1024
#define NE    8

typedef __bf16 bf16_t;
typedef __bf16 bf16x8 __attribute__((ext_vector_type(8)));
typedef float  f32x4  __attribute__((ext_vector_type(4)));

typedef __attribute__((address_space(3))) void       as3_void;
typedef __attribute__((address_space(1))) const void as1_void;
#define GLDS16(src, dst) \
  __builtin_amdgcn_global_load_lds((as1_void*)(src), (as3_void*)(dst), 16, 0, 0)

#define FENCE() asm volatile("" ::: "memory")
#define BARRIER() do { FENCE(); __builtin_amdgcn_s_barrier(); FENCE(); } while (0)
#define LGKM_WAIT() do { \
    asm volatile("s_waitcnt lgkmcnt(0)" ::: "memory"); \
    __builtin_amdgcn_sched_barrier(0); } while (0)
#define VMW_RING() do { \
    if (wid < 4) asm volatile("s_waitcnt vmcnt(4)" ::: "memory"); \
    else         asm volatile("s_waitcnt vmcnt(3)" ::: "memory"); } while (0)
#define VM_WAIT0() asm volatile("s_waitcnt vmcnt(0)" ::: "memory")

// ---------------- gate body: one wave per token ----------------------------
__device__ __forceinline__ void gate_body(int bid, const float* __restrict__ x,
                                          const float* __restrict__ Wg,
                                          const float* __restrict__ bg,
                                          int* __restrict__ einfo,
                                          float2* __restrict__ gpair,
                                          bf16_t* __restrict__ xb) {
  int wid  = threadIdx.x >> 6;
  int lane = threadIdx.x & 63;
  int t = bid * 4 + wid;

  const float4* xr = (const float4*)(x + (size_t)t * DIM);
  float4 xv4[4];
  float sf[NE];
#pragma unroll
  for (int e = 0; e < NE; ++e) sf[e] = 0.f;

#pragma unroll
  for (int i = 0; i < 4; ++i) {
    int q = lane + 64 * i;
    float4 xv = xr[q];
    xv4[i] = xv;
    int d = q * 4;
#pragma unroll
    for (int c = 0; c < 4; ++c) {
      float xc = (&xv.x)[c];
      const float4* wr = (const float4*)(Wg + (size_t)(d + c) * NE);
      float4 w0 = wr[0], w1 = wr[1];
      sf[0] += xc * w0.x; sf[1] += xc * w0.y;
      sf[2] += xc * w0.z; sf[3] += xc * w0.w;
      sf[4] += xc * w1.x; sf[5] += xc * w1.y;
      sf[6] += xc * w1.z; sf[7] += xc * w1.w;
    }
  }

  ushort4* xbr = (ushort4*)(xb + (size_t)t * DIM);
#pragma unroll
  for (int i = 0; i < 4; ++i) {
    union { bf16_t b[4]; ushort4 u; } cv;
    cv.b[0] = (bf16_t)xv4[i].x; cv.b[1] = (bf16_t)xv4[i].y;
    cv.b[2] = (bf16_t)xv4[i].z; cv.b[3] = (bf16_t)xv4[i].w;
    xbr[lane + 64 * i] = cv.u;
  }

  double s[NE];
#pragma unroll
  for (int e = 0; e < NE; ++e) s[e] = (double)sf[e];
#pragma unroll
  for (int off = 32; off > 0; off >>= 1) {
#pragma unroll
    for (int e = 0; e < NE; ++e) s[e] += __shfl_xor(s[e], off);
  }

  if (lane == 0) {
    double v0 = -1e300, v1 = -1e300;
    int i0 = 0, i1 = 0;
#pragma unroll
    for (int e = 0; e < NE; ++e) {
      double v = s[e] + (double)bg[e];
      if (v > v0)      { v1 = v0; i1 = i0; v0 = v; i0 = e; }
      else if (v > v1) { v1 = v;  i1 = e; }
    }
    float ex = expf((float)(v1 - v0));
    float inv = 1.0f / (1.0f + ex);
    einfo[t] = i0 | (i1 << 8);
    gpair[t] = make_float2(inv, ex * inv);
  }
}

// ---- transpose v3: 64r x 128c tile, 4x4 register micro-transpose ----------
__device__ __forceinline__ void tr_body(const float* __restrict__ W,
                                        bf16_t* __restrict__ Wt, int R, int C,
                                        int bx, int by, int e, char* lds) {
  size_t ebase = (size_t)e * R * C;
  const int r0 = by * 64, c0 = bx * 128;
  const int tid = threadIdx.x;
#pragma unroll
  for (int half = 0; half < 2; ++half) {
    int b = tid + 256 * half;
    int bc = b & 31, br = b >> 5;
    int r4 = br * 4;
    const float* src = W + ebase + (size_t)(r0 + r4) * C + c0 + bc * 4;
    float4 v0 = *(const float4*)(src);
    float4 v1 = *(const float4*)(src + C);
    float4 v2 = *(const float4*)(src + 2 * (size_t)C);
    float4 v3 = *(const float4*)(src + 3 * (size_t)C);
#pragma unroll
    for (int j = 0; j < 4; ++j) {
      int oc = bc * 4 + j;
      union { bf16_t b4[4]; unsigned long long u; } cv;
      cv.b4[0] = (bf16_t)(&v0.x)[j];
      cv.b4[1] = (bf16_t)(&v1.x)[j];
      cv.b4[2] = (bf16_t)(&v2.x)[j];
      cv.b4[3] = (bf16_t)(&v3.x)[j];
      int cswz = (r4 >> 3) ^ ((oc >> 3) & 7);
      *(unsigned long long*)(lds + oc * 144 + cswz * 16 + (r4 & 7) * 2) = cv.u;
    }
  }
  __syncthreads();
#pragma unroll
  for (int p = 0; p < 4; ++p) {
    int q = tid + 256 * p;
    int oc = q >> 3, seg = q & 7;
    int cswz = seg ^ ((oc >> 3) & 7);
    uint4 val = *(const uint4*)(lds + oc * 144 + cswz * 16);
    *(uint4*)&Wt[ebase + (size_t)(c0 + oc) * R + r0 + seg * 8] = val;
  }
}

// ---------------- front: gate + trW1 + trW2 in one launch ------------------
#define NB_GATE (T_TOK / 4)                            // 1024
#define NB_TR1  ((DIM / 64) * (HID / 128) * NE)        // 2048
#define NB_TR2  ((HID / 64) * (OUTD / 128) * NE)       // 2048
__global__ void k_front(const float* __restrict__ x, const float* __restrict__ Wg,
                        const float* __restrict__ bg, int* __restrict__ einfo,
                        float2* __restrict__ gpair, bf16_t* __restrict__ xb,
                        const float* __restrict__ W1, bf16_t* __restrict__ W1t,
                        const float* __restrict__ W2, bf16_t* __restrict__ W2t) {
  __shared__ __align__(16) char lds[18432];
  int bid = blockIdx.x;
  if (bid < NB_GATE) {
    gate_body(bid, x, Wg, bg, einfo, gpair, xb);
  } else if (bid < NB_GATE + NB_TR1) {
    int i = bid - NB_GATE;
    int nbx = HID / 128, nby = DIM / 64;
    tr_body(W1, W1t, DIM, HID, i % nbx, (i / nbx) % nby, i / (nbx * nby), lds);
  } else {
    int i = bid - NB_GATE - NB_TR1;
    int nbx = OUTD / 128, nby = HID / 64;
    tr_body(W2, W2t, HID, OUTD, i % nbx, (i / nbx) % nby, i / (nbx * nby), lds);
  }
}

// ------- binning: ballot stream-compaction, wave w = expert w ---------------
__global__ void k_bin(const int* __restrict__ einfo, const float2* __restrict__ gpair,
                      int* __restrict__ cnt, int* __restrict__ offs,
                      int* __restrict__ elist, float* __restrict__ egate) {
  __shared__ int scnt[NE];
  int w = threadIdx.x >> 6;
  int lane = threadIdx.x & 63;
  unsigned long long below = (lane == 0) ? 0ull : ((~0ull) >> (64 - lane));
  int base = 0;
  for (int c = 0; c < T_TOK / 64; ++c) {
    int t = c * 64 + lane;
    int ei = einfo[t];
    float2 g = gpair[t];
    int e0 = ei & 0xff, e1 = ei >> 8;
    bool m0 = (e0 == w);
    bool m  = m0 || (e1 == w);
    unsigned long long mask = __ballot(m);
    if (m) {
      int pos = base + (int)__popcll(mask & below);
      elist[w * T_TOK + pos] = t;
      egate[w * T_TOK + pos] = m0 ? g.x : g.y;
    }
    base += (int)__popcll(mask);
  }
  if (lane == 0) scnt[w] = base;
  __syncthreads();
  if (threadIdx.x == 0) {
    int a = 0;
#pragma unroll
    for (int e = 0; e < NE; ++e) {
      cnt[e] = scnt[e];
      offs[e] = a;
      a += scnt[e];
    }
    offs[NE] = a;
  }
}

// =========== 2-pair KTILE, BM=192 (A halves 96r), BN=256, BK=64 =============
#define STAGE_A(TT, HH) do { \
    char* _d = smem + (((TT) & 1) * 24576) + ((HH) * 12288); \
    GLDS16(Abase + offA[HH][0] + (TT) * 128, _d + tid * 16); \
    if (tid < 256) GLDS16(Abase + offA[HH][1] + (TT) * 128, _d + (512 + tid) * 16); \
  } while (0)

#define STAGE_B(TT, HH) do { \
    char* _d = smem + 49152 + (((TT) & 1) * 32768) + ((HH) * 16384); \
    GLDS16(Bbase + offB[HH][0] + (TT) * 128, _d + tid * 16); \
    GLDS16(Bbase + offB[HH][1] + (TT) * 128, _d + (512 + tid) * 16); \
  } while (0)

#define MFMA_Q(AF, BF, AH, BH) \
    _Pragma("unroll") for (int i = 0; i < 3; ++i) \
      _Pragma("unroll") for (int j = 0; j < 2; ++j) \
        _Pragma("unroll") for (int kk = 0; kk < 2; ++kk) \
          acc[(AH) * 3 + i][(BH) * 2 + j] = \
            __builtin_amdgcn_mfma_f32_16x16x32_bf16(AF[i][kk], BF[j][kk], \
                acc[(AH) * 3 + i][(BH) * 2 + j], 0, 0, 0)

#define RD_AF(SL) \
    _Pragma("unroll") for (int i = 0; i < 3; ++i) \
      _Pragma("unroll") for (int kk = 0; kk < 2; ++kk) \
        af[i][kk] = *(const bf16x8*)((SL) + rdA[i][kk])

#define KTILE(TT, NTc) do { \
    const char* _a0 = smem + (((TT) & 1) * 24576); \
    const char* _a1 = smem + (((TT) & 1) * 24576) + 12288; \
    const char* _b0 = smem + 49152 + (((TT) & 1) * 32768); \
    const char* _b1 = smem + 49152 + (((TT) & 1) * 32768) + 16384; \
    bf16x8 af[3][2], bf0[2][2], bf1[2][2]; \
    RD_AF(_a0); \
    _Pragma("unroll") for (int j = 0; j < 2; ++j) \
      _Pragma("unroll") for (int kk = 0; kk < 2; ++kk) { \
        bf0[j][kk] = *(const bf16x8*)(_b0 + rdB[j][kk]); \
        bf1[j][kk] = *(const bf16x8*)(_b1 + rdB[j][kk]); \
      } \
    if ((TT) + 1 < (NTc)) { STAGE_A((TT) + 1, 1); STAGE_B((TT) + 1, 1); } \
    BARRIER(); LGKM_WAIT(); \
    __builtin_amdgcn_s_setprio(1); \
    MFMA_Q(af, bf0, 0, 0); MFMA_Q(af, bf1, 0, 1); \
    __builtin_amdgcn_s_setprio(0); BARRIER(); \
    RD_AF(_a1); \
    if ((TT) + 2 < (NTc)) { STAGE_A((TT) + 2, 0); STAGE_B((TT) + 2, 0); \
      VMW_RING(); } \
    else { VM_WAIT0(); } \
    BARRIER(); LGKM_WAIT(); \
    __builtin_amdgcn_s_setprio(1); \
    MFMA_Q(af, bf0, 1, 0); MFMA_Q(af, bf1, 1, 1); \
    __builtin_amdgcn_s_setprio(0); BARRIER(); \
  } while (0)

// ---------------- GEMM1: h = relu(gather(x) @ W1 + b1) ----------------------
__launch_bounds__(512, 2)
__global__ void k_gemm1(const bf16_t* __restrict__ xb, const bf16_t* __restrict__ W1t,
                        const float* __restrict__ b1, const int* __restrict__ cnt,
                        const int* __restrict__ offs, const int* __restrict__ elist,
                        bf16_t* __restrict__ hbuf) {
  const int e = blockIdx.z;
  const int count = cnt[e];
  const int rt = blockIdx.y;
  if (rt * 192 >= count) return;
  const int nt = blockIdx.x;

  __shared__ __align__(16) char smem[114688];

  const int tid = threadIdx.x, lane = tid & 63, wid = tid >> 6;
  const int wm = wid >> 2, wn = wid & 3;
  const int fr = lane & 15, lh = lane >> 4;

  unsigned offA[2][2], offB[2][2];
#pragma unroll
  for (int j = 0; j < 2; ++j) {
    int q = j * 512 + tid;
    int r = q >> 3, sfg = (q & 7) ^ (r & 7);
#pragma unroll
    for (int h = 0; h < 2; ++h) {
      int ar = r < 96 ? r : 95;
      int gr = rt * 192 + h * 96 + ar;
      if (gr > count - 1) gr = count - 1;
      int tok = elist[e * T_TOK + gr];
      offA[h][j] = (unsigned)((tok * DIM + sfg * 8) * 2);
      int brow = nt * 256 + h * 128 + r;
      offB[h][j] = (unsigned)(((e * HID + brow) * DIM + sfg * 8) * 2);
    }
  }
  unsigned rdA[3][2], rdB[2][2];
#pragma unroll
  for (int i = 0; i < 3; ++i) {
    int r = wm * 48 + i * 16 + fr;
#pragma unroll
    for (int kk = 0; kk < 2; ++kk)
      rdA[i][kk] = (unsigned)(r * 128 + (((kk * 4 + lh) ^ (r & 7)) * 16));
  }
#pragma unroll
  for (int j = 0; j < 2; ++j) {
    int r = wn * 32 + j * 16 + fr;
#pragma unroll
    for (int kk = 0; kk < 2; ++kk)
      rdB[j][kk] = (unsigned)(r * 128 + (((kk * 4 + lh) ^ (r & 7)) * 16));
  }

  const char* Abase = (const char*)xb;
  const char* Bbase = (const char*)W1t;

  f32x4 acc[6][4];
#pragma unroll
  for (int i = 0; i < 6; ++i)
#pragma unroll
    for (int j = 0; j < 4; ++j) acc[i][j] = (f32x4){0.f, 0.f, 0.f, 0.f};

  const int NT = DIM / 64;  // 16
  STAGE_A(0, 0); STAGE_B(0, 0); STAGE_A(0, 1); STAGE_B(0, 1);
  STAGE_A(1, 0); STAGE_B(1, 0);
  VMW_RING();
  BARRIER();

  for (int t = 0; t < NT; ++t) KTILE(t, NT);

  const int hbase = offs[e];
#pragma unroll
  for (int mi = 0; mi < 6; ++mi) {
#pragma unroll
    for (int rr = 0; rr < 4; ++rr) {
      int rowp = rt * 192 + (mi / 3) * 96 + wm * 48 + (mi % 3) * 16 + lh * 4 + rr;
      if (rowp < count) {
        size_t hrow = (size_t)(hbase + rowp) * HID;
#pragma unroll
        for (int nj = 0; nj < 4; ++nj) {
          int col = nt * 256 + (nj >> 1) * 128 + wn * 32 + (nj & 1) * 16 + fr;
          float v = acc[mi][nj][rr] + b1[e * HID + col];
          hbuf[hrow + col] = (bf16_t)(v > 0.f ? v : 0.f);
        }
      }
    }
  }
}

// ------- GEMM2 (+fused combine): out[tok] += gate*(h @ W2 + b2) -------------
// Each out element receives exactly 2 commutative fp32 atomicAdds onto a
// zeroed base -> bitwise deterministic across replays.
__launch_bounds__(512, 2)
__global__ void k_gemm2(const bf16_t* __restrict__ hbuf, const bf16_t* __restrict__ W2t,
                        const float* __restrict__ b2, const int* __restrict__ cnt,
                        const int* __restrict__ offs, const int* __restrict__ elist,
                        const float* __restrict__ egate, float* __restrict__ out) {
  const int e = blockIdx.z;
  const int count = cnt[e];
  const int rt = blockIdx.y;
  if (rt * 192 >= count) return;
  const int nt = blockIdx.x;

  __shared__ __align__(16) char smem[114688];

  const int tid = threadIdx.x, lane = tid & 63, wid = tid >> 6;
  const int wm = wid >> 2, wn = wid & 3;
  const int fr = lane & 15, lh = lane >> 4;
  const int hbase = offs[e];

  unsigned offA[2][2], offB[2][2];
#pragma unroll
  for (int j = 0; j < 2; ++j) {
    int q = j * 512 + tid;
    int r = q >> 3, sfg = (q & 7) ^ (r & 7);
#pragma unroll
    for (int h = 0; h < 2; ++h) {
      int ar = r < 96 ? r : 95;
      int gr = rt * 192 + h * 96 + ar;
      if (gr > count - 1) gr = count - 1;
      offA[h][j] = (unsigned)(((hbase + gr) * HID + sfg * 8) * 2);
      int brow = nt * 256 + h * 128 + r;
      offB[h][j] = (unsigned)(((e * OUTD + brow) * HID + sfg * 8) * 2);
    }
  }
  unsigned rdA[3][2], rdB[2][2];
#pragma unroll
  for (int i = 0; i < 3; ++i) {
    int r = wm * 48 + i * 16 + fr;
#pragma unroll
    for (int kk = 0; kk < 2; ++kk)
      rdA[i][kk] = (unsigned)(r * 128 + (((kk * 4 + lh) ^ (r & 7)) * 16));
  }
#pragma unroll
  for (int j = 0; j < 2; ++j) {
    int r = wn * 32 + j * 16 + fr;
#pragma unroll
    for (int kk = 0; kk < 2; ++kk)
      rdB[j][kk] = (unsigned)(r * 128 + (((kk * 4 + lh) ^ (r & 7)) * 16));
  }

  const char* Abase = (const char*)hbuf;
  const char* Bbase = (const char*)W2t;

  f32x4 acc[6][4];
#pragma unroll
  for (int i = 0; i < 6; ++i)
#pragma unroll
    for (int j = 0; j < 4; ++j) acc[i][j] = (f32x4){0.f, 0.f, 0.f, 0.f};

  const int NT = HID / 64;  // 32
  STAGE_A(0, 0); STAGE_B(0, 0); STAGE_A(0, 1); STAGE_B(0, 1);
  STAGE_A(1, 0); STAGE_B(1, 0);
  VMW_RING();
  BARRIER();

  for (int t = 0; t < NT; ++t) KTILE(t, NT);

#pragma unroll
  for (int mi = 0; mi < 6; ++mi) {
#pragma unroll
    for (int rr = 0; rr < 4; ++rr) {
      int rowp = rt * 192 + (mi / 3) * 96 + wm * 48 + (mi % 3) * 16 + lh * 4 + rr;
      if (rowp < count) {
        int tokv   = elist[e * T_TOK + rowp];
        float gate = egate[e * T_TOK + rowp];
        float* orow = out + (size_t)tokv * OUTD;
#pragma unroll
        for (int nj = 0; nj < 4; ++nj) {
          int col = nt * 256 + (nj >> 1) * 128 + wn * 32 + (nj & 1) * 16 + fr;
          atomicAdd(&orow[col], gate * (acc[mi][nj][rr] + b2[e * OUTD + col]));
        }
      }
    }
  }
}

// ---------------------------------------------------------------------------
extern "C" void kernel_launch(void* const* d_in, const int* in_sizes, int n_in,
                              void* d_out, int out_size, void* d_ws, size_t ws_size,
                              hipStream_t stream) {
  const float* x  = (const float*)d_in[0];
  const float* Wg = (const float*)d_in[1];
  const float* bg = (const float*)d_in[2];
  const float* W1 = (const float*)d_in[3];
  const float* b1 = (const float*)d_in[4];
  const float* W2 = (const float*)d_in[5];
  const float* b2 = (const float*)d_in[6];
  float* out = (float*)d_out;

  char* ws = (char*)d_ws;
  int*    cnt    = (int*)(ws);
  int*    offs   = (int*)(ws + 1024);
  int*    einfo  = (int*)(ws + 36864);                      // 16 KB
  float2* gpair  = (float2*)(ws + 53248);                   // 32 KB
  int*    elist  = (int*)(ws + 131072);                     // 128 KB
  float*  egate  = (float*)(ws + 262144);                   // 128 KB
  bf16_t* W1t    = (bf16_t*)(ws + (1u << 20));              // 32 MB
  bf16_t* W2t    = (bf16_t*)(ws + (1u << 20) + (32u << 20));// 32 MB
  bf16_t* xb     = (bf16_t*)(ws + (1u << 20) + (64u << 20));// 8 MB
  bf16_t* hbuf   = (bf16_t*)(ws + (1u << 20) + (72u << 20));// 32 MB

  hipMemsetAsync(out, 0, (size_t)out_size * sizeof(float), stream);

  k_front<<<NB_GATE + NB_TR1 + NB_TR2, 256, 0, stream>>>(
      x, Wg, bg, einfo, gpair, xb, W1, W1t, W2, W2t);
  k_bin<<<1, 512, 0, stream>>>(einfo, gpair, cnt, offs, elist, egate);

  k_gemm1<<<dim3(HID / 256, 22, NE), 512, 0, stream>>>(
      xb, W1t, b1, cnt, offs, elist, hbuf);
  k_gemm2<<<dim3(OUTD / 256, 22, NE), 512, 0, stream>>>(
      hbuf, W2t, b2, cnt, offs, elist, egate, out);
}

// Round 21
// 198.582 us; speedup vs baseline: 1.1441x; 1.1441x over previous
//
#include <hip/hip_runtime.h>
#include <math.h>

// MoE: T=4096, D=1024, H=2048, O=1024, E=8, top-2.
// Routed sparse: 68.7 GFLOP bf16 MFMA. GEMMs: round-11 proven KTILE config
// (BM=192/BN=256/BK=64, 8 waves, 2 barrier-pairs/K-tile, counted per-wave
// vmcnt ring, setprio, chunk-XOR swizzle, LDS 112 KB). Front: gate + both
// transposes (v3 register micro-transpose). Epilogue: y + combine (atomics
// refuted twice: r14, r20). THIS ROUND: 1D XCD-chunked grids (T1, m192/m204)
// with rt-minor decode so co-resident blocks on an XCD share (e,nt) B panels
// -> staging hits XCD-local L2 instead of LLC/HBM (latency-bound ring).

#define T_TOK 4096
#define DIM   1024
#define HID   2048
#define OUTD  1024
#define NE    8

typedef __bf16 bf16_t;
typedef __bf16 bf16x8 __attribute__((ext_vector_type(8)));
typedef float  f32x4  __attribute__((ext_vector_type(4)));

typedef __attribute__((address_space(3))) void       as3_void;
typedef __attribute__((address_space(1))) const void as1_void;
#define GLDS16(src, dst) \
  __builtin_amdgcn_global_load_lds((as1_void*)(src), (as3_void*)(dst), 16, 0, 0)

#define FENCE() asm volatile("" ::: "memory")
#define BARRIER() do { FENCE(); __builtin_amdgcn_s_barrier(); FENCE(); } while (0)
#define LGKM_WAIT() do { \
    asm volatile("s_waitcnt lgkmcnt(0)" ::: "memory"); \
    __builtin_amdgcn_sched_barrier(0); } while (0)
#define VMW_RING() do { \
    if (wid < 4) asm volatile("s_waitcnt vmcnt(4)" ::: "memory"); \
    else         asm volatile("s_waitcnt vmcnt(3)" ::: "memory"); } while (0)
#define VM_WAIT0() asm volatile("s_waitcnt vmcnt(0)" ::: "memory")

// ---------------- gate body: one wave per token ----------------------------
__device__ __forceinline__ void gate_body(int bid, const float* __restrict__ x,
                                          const float* __restrict__ Wg,
                                          const float* __restrict__ bg,
                                          int* __restrict__ einfo,
                                          float2* __restrict__ gpair,
                                          bf16_t* __restrict__ xb) {
  int wid  = threadIdx.x >> 6;
  int lane = threadIdx.x & 63;
  int t = bid * 4 + wid;

  const float4* xr = (const float4*)(x + (size_t)t * DIM);
  float4 xv4[4];
  float sf[NE];
#pragma unroll
  for (int e = 0; e < NE; ++e) sf[e] = 0.f;

#pragma unroll
  for (int i = 0; i < 4; ++i) {
    int q = lane + 64 * i;
    float4 xv = xr[q];
    xv4[i] = xv;
    int d = q * 4;
#pragma unroll
    for (int c = 0; c < 4; ++c) {
      float xc = (&xv.x)[c];
      const float4* wr = (const float4*)(Wg + (size_t)(d + c) * NE);
      float4 w0 = wr[0], w1 = wr[1];
      sf[0] += xc * w0.x; sf[1] += xc * w0.y;
      sf[2] += xc * w0.z; sf[3] += xc * w0.w;
      sf[4] += xc * w1.x; sf[5] += xc * w1.y;
      sf[6] += xc * w1.z; sf[7] += xc * w1.w;
    }
  }

  ushort4* xbr = (ushort4*)(xb + (size_t)t * DIM);
#pragma unroll
  for (int i = 0; i < 4; ++i) {
    union { bf16_t b[4]; ushort4 u; } cv;
    cv.b[0] = (bf16_t)xv4[i].x; cv.b[1] = (bf16_t)xv4[i].y;
    cv.b[2] = (bf16_t)xv4[i].z; cv.b[3] = (bf16_t)xv4[i].w;
    xbr[lane + 64 * i] = cv.u;
  }

  double s[NE];
#pragma unroll
  for (int e = 0; e < NE; ++e) s[e] = (double)sf[e];
#pragma unroll
  for (int off = 32; off > 0; off >>= 1) {
#pragma unroll
    for (int e = 0; e < NE; ++e) s[e] += __shfl_xor(s[e], off);
  }

  if (lane == 0) {
    double v0 = -1e300, v1 = -1e300;
    int i0 = 0, i1 = 0;
#pragma unroll
    for (int e = 0; e < NE; ++e) {
      double v = s[e] + (double)bg[e];
      if (v > v0)      { v1 = v0; i1 = i0; v0 = v; i0 = e; }
      else if (v > v1) { v1 = v;  i1 = e; }
    }
    float ex = expf((float)(v1 - v0));
    float inv = 1.0f / (1.0f + ex);
    einfo[t] = i0 | (i1 << 8);
    gpair[t] = make_float2(inv, ex * inv);
  }
}

// ---- transpose v3: 64r x 128c tile, 4x4 register micro-transpose ----------
__device__ __forceinline__ void tr_body(const float* __restrict__ W,
                                        bf16_t* __restrict__ Wt, int R, int C,
                                        int bx, int by, int e, char* lds) {
  size_t ebase = (size_t)e * R * C;
  const int r0 = by * 64, c0 = bx * 128;
  const int tid = threadIdx.x;
#pragma unroll
  for (int half = 0; half < 2; ++half) {
    int b = tid + 256 * half;
    int bc = b & 31, br = b >> 5;
    int r4 = br * 4;
    const float* src = W + ebase + (size_t)(r0 + r4) * C + c0 + bc * 4;
    float4 v0 = *(const float4*)(src);
    float4 v1 = *(const float4*)(src + C);
    float4 v2 = *(const float4*)(src + 2 * (size_t)C);
    float4 v3 = *(const float4*)(src + 3 * (size_t)C);
#pragma unroll
    for (int j = 0; j < 4; ++j) {
      int oc = bc * 4 + j;
      union { bf16_t b4[4]; unsigned long long u; } cv;
      cv.b4[0] = (bf16_t)(&v0.x)[j];
      cv.b4[1] = (bf16_t)(&v1.x)[j];
      cv.b4[2] = (bf16_t)(&v2.x)[j];
      cv.b4[3] = (bf16_t)(&v3.x)[j];
      int cswz = (r4 >> 3) ^ ((oc >> 3) & 7);
      *(unsigned long long*)(lds + oc * 144 + cswz * 16 + (r4 & 7) * 2) = cv.u;
    }
  }
  __syncthreads();
#pragma unroll
  for (int p = 0; p < 4; ++p) {
    int q = tid + 256 * p;
    int oc = q >> 3, seg = q & 7;
    int cswz = seg ^ ((oc >> 3) & 7);
    uint4 val = *(const uint4*)(lds + oc * 144 + cswz * 16);
    *(uint4*)&Wt[ebase + (size_t)(c0 + oc) * R + r0 + seg * 8] = val;
  }
}

// ---------------- front: gate + trW1 + trW2 in one launch ------------------
#define NB_GATE (T_TOK / 4)                            // 1024
#define NB_TR1  ((DIM / 64) * (HID / 128) * NE)        // 2048
#define NB_TR2  ((HID / 64) * (OUTD / 128) * NE)       // 2048
__global__ void k_front(const float* __restrict__ x, const float* __restrict__ Wg,
                        const float* __restrict__ bg, int* __restrict__ einfo,
                        float2* __restrict__ gpair, bf16_t* __restrict__ xb,
                        const float* __restrict__ W1, bf16_t* __restrict__ W1t,
                        const float* __restrict__ W2, bf16_t* __restrict__ W2t) {
  __shared__ __align__(16) char lds[18432];
  int bid = blockIdx.x;
  if (bid < NB_GATE) {
    gate_body(bid, x, Wg, bg, einfo, gpair, xb);
  } else if (bid < NB_GATE + NB_TR1) {
    int i = bid - NB_GATE;
    int nbx = HID / 128, nby = DIM / 64;
    tr_body(W1, W1t, DIM, HID, i % nbx, (i / nbx) % nby, i / (nbx * nby), lds);
  } else {
    int i = bid - NB_GATE - NB_TR1;
    int nbx = OUTD / 128, nby = HID / 64;
    tr_body(W2, W2t, HID, OUTD, i % nbx, (i / nbx) % nby, i / (nbx * nby), lds);
  }
}

// ------- binning: ballot stream-compaction, wave w = expert w ---------------
__global__ void k_bin(const int* __restrict__ einfo, const float2* __restrict__ gpair,
                      int* __restrict__ cnt, int* __restrict__ offs,
                      int* __restrict__ elist, float* __restrict__ egate,
                      int* __restrict__ tokrec) {
  __shared__ int scnt[NE];
  int w = threadIdx.x >> 6;
  int lane = threadIdx.x & 63;
  unsigned long long below = (lane == 0) ? 0ull : ((~0ull) >> (64 - lane));
  int base = 0;
  for (int c = 0; c < T_TOK / 64; ++c) {
    int t = c * 64 + lane;
    int ei = einfo[t];
    float2 g = gpair[t];
    int e0 = ei & 0xff, e1 = ei >> 8;
    bool m0 = (e0 == w);
    bool m  = m0 || (e1 == w);
    unsigned long long mask = __ballot(m);
    if (m) {
      int pos = base + (int)__popcll(mask & below);
      elist[w * T_TOK + pos] = t;
      egate[w * T_TOK + pos] = m0 ? g.x : g.y;
      tokrec[2 * t + (m0 ? 0 : 1)] = (w << 16) | pos;
    }
    base += (int)__popcll(mask);
  }
  if (lane == 0) scnt[w] = base;
  __syncthreads();
  if (threadIdx.x == 0) {
    int a = 0;
#pragma unroll
    for (int e = 0; e < NE; ++e) {
      cnt[e] = scnt[e];
      offs[e] = a;
      a += scnt[e];
    }
    offs[NE] = a;
  }
}

// =========== 2-pair KTILE, BM=192 (A halves 96r), BN=256, BK=64 =============
#define STAGE_A(TT, HH) do { \
    char* _d = smem + (((TT) & 1) * 24576) + ((HH) * 12288); \
    GLDS16(Abase + offA[HH][0] + (TT) * 128, _d + tid * 16); \
    if (tid < 256) GLDS16(Abase + offA[HH][1] + (TT) * 128, _d + (512 + tid) * 16); \
  } while (0)

#define STAGE_B(TT, HH) do { \
    char* _d = smem + 49152 + (((TT) & 1) * 32768) + ((HH) * 16384); \
    GLDS16(Bbase + offB[HH][0] + (TT) * 128, _d + tid * 16); \
    GLDS16(Bbase + offB[HH][1] + (TT) * 128, _d + (512 + tid) * 16); \
  } while (0)

#define MFMA_Q(AF, BF, AH, BH) \
    _Pragma("unroll") for (int i = 0; i < 3; ++i) \
      _Pragma("unroll") for (int j = 0; j < 2; ++j) \
        _Pragma("unroll") for (int kk = 0; kk < 2; ++kk) \
          acc[(AH) * 3 + i][(BH) * 2 + j] = \
            __builtin_amdgcn_mfma_f32_16x16x32_bf16(AF[i][kk], BF[j][kk], \
                acc[(AH) * 3 + i][(BH) * 2 + j], 0, 0, 0)

#define RD_AF(SL) \
    _Pragma("unroll") for (int i = 0; i < 3; ++i) \
      _Pragma("unroll") for (int kk = 0; kk < 2; ++kk) \
        af[i][kk] = *(const bf16x8*)((SL) + rdA[i][kk])

#define KTILE(TT, NTc) do { \
    const char* _a0 = smem + (((TT) & 1) * 24576); \
    const char* _a1 = smem + (((TT) & 1) * 24576) + 12288; \
    const char* _b0 = smem + 49152 + (((TT) & 1) * 32768); \
    const char* _b1 = smem + 49152 + (((TT) & 1) * 32768) + 16384; \
    bf16x8 af[3][2], bf0[2][2], bf1[2][2]; \
    RD_AF(_a0); \
    _Pragma("unroll") for (int j = 0; j < 2; ++j) \
      _Pragma("unroll") for (int kk = 0; kk < 2; ++kk) { \
        bf0[j][kk] = *(const bf16x8*)(_b0 + rdB[j][kk]); \
        bf1[j][kk] = *(const bf16x8*)(_b1 + rdB[j][kk]); \
      } \
    if ((TT) + 1 < (NTc)) { STAGE_A((TT) + 1, 1); STAGE_B((TT) + 1, 1); } \
    BARRIER(); LGKM_WAIT(); \
    __builtin_amdgcn_s_setprio(1); \
    MFMA_Q(af, bf0, 0, 0); MFMA_Q(af, bf1, 0, 1); \
    __builtin_amdgcn_s_setprio(0); BARRIER(); \
    RD_AF(_a1); \
    if ((TT) + 2 < (NTc)) { STAGE_A((TT) + 2, 0); STAGE_B((TT) + 2, 0); \
      VMW_RING(); } \
    else { VM_WAIT0(); } \
    BARRIER(); LGKM_WAIT(); \
    __builtin_amdgcn_s_setprio(1); \
    MFMA_Q(af, bf0, 1, 0); MFMA_Q(af, bf1, 1, 1); \
    __builtin_amdgcn_s_setprio(0); BARRIER(); \
  } while (0)

// ---------------- GEMM1: h = relu(gather(x) @ W1 + b1) ----------------------
// 1D grid 1408 = 8 XCD chunks x 176 work; work = (e,nt) group-major, rt-minor.
__launch_bounds__(512, 2)
__global__ void k_gemm1(const bf16_t* __restrict__ xb, const bf16_t* __restrict__ W1t,
                        const float* __restrict__ b1, const int* __restrict__ cnt,
                        const int* __restrict__ offs, const int* __restrict__ elist,
                        bf16_t* __restrict__ hbuf) {
  const int wk = (blockIdx.x & 7) * 176 + (blockIdx.x >> 3);
  const int rt = wk % 22;
  const int g  = wk / 22;
  const int e  = g >> 3, nt = g & 7;
  const int count = cnt[e];
  if (rt * 192 >= count) return;

  __shared__ __align__(16) char smem[114688];

  const int tid = threadIdx.x, lane = tid & 63, wid = tid >> 6;
  const int wm = wid >> 2, wn = wid & 3;
  const int fr = lane & 15, lh = lane >> 4;

  unsigned offA[2][2], offB[2][2];
#pragma unroll
  for (int j = 0; j < 2; ++j) {
    int q = j * 512 + tid;
    int r = q >> 3, sfg = (q & 7) ^ (r & 7);
#pragma unroll
    for (int h = 0; h < 2; ++h) {
      int ar = r < 96 ? r : 95;
      int gr = rt * 192 + h * 96 + ar;
      if (gr > count - 1) gr = count - 1;
      int tok = elist[e * T_TOK + gr];
      offA[h][j] = (unsigned)((tok * DIM + sfg * 8) * 2);
      int brow = nt * 256 + h * 128 + r;
      offB[h][j] = (unsigned)(((e * HID + brow) * DIM + sfg * 8) * 2);
    }
  }
  unsigned rdA[3][2], rdB[2][2];
#pragma unroll
  for (int i = 0; i < 3; ++i) {
    int r = wm * 48 + i * 16 + fr;
#pragma unroll
    for (int kk = 0; kk < 2; ++kk)
      rdA[i][kk] = (unsigned)(r * 128 + (((kk * 4 + lh) ^ (r & 7)) * 16));
  }
#pragma unroll
  for (int j = 0; j < 2; ++j) {
    int r = wn * 32 + j * 16 + fr;
#pragma unroll
    for (int kk = 0; kk < 2; ++kk)
      rdB[j][kk] = (unsigned)(r * 128 + (((kk * 4 + lh) ^ (r & 7)) * 16));
  }

  const char* Abase = (const char*)xb;
  const char* Bbase = (const char*)W1t;

  f32x4 acc[6][4];
#pragma unroll
  for (int i = 0; i < 6; ++i)
#pragma unroll
    for (int j = 0; j < 4; ++j) acc[i][j] = (f32x4){0.f, 0.f, 0.f, 0.f};

  const int NT = DIM / 64;  // 16
  STAGE_A(0, 0); STAGE_B(0, 0); STAGE_A(0, 1); STAGE_B(0, 1);
  STAGE_A(1, 0); STAGE_B(1, 0);
  VMW_RING();
  BARRIER();

  for (int t = 0; t < NT; ++t) KTILE(t, NT);

  const int hbase = offs[e];
#pragma unroll
  for (int mi = 0; mi < 6; ++mi) {
#pragma unroll
    for (int rr = 0; rr < 4; ++rr) {
      int rowp = rt * 192 + (mi / 3) * 96 + wm * 48 + (mi % 3) * 16 + lh * 4 + rr;
      if (rowp < count) {
        size_t hrow = (size_t)(hbase + rowp) * HID;
#pragma unroll
        for (int nj = 0; nj < 4; ++nj) {
          int col = nt * 256 + (nj >> 1) * 128 + wn * 32 + (nj & 1) * 16 + fr;
          float v = acc[mi][nj][rr] + b1[e * HID + col];
          hbuf[hrow + col] = (bf16_t)(v > 0.f ? v : 0.f);
        }
      }
    }
  }
}

// ---------------- GEMM2: y[slot] = gate * (h @ W2 + b2) ---------------------
// 1D grid 704 = 8 XCD chunks x 88 work; work = (e,nt) group-major, rt-minor.
__launch_bounds__(512, 2)
__global__ void k_gemm2(const bf16_t* __restrict__ hbuf, const bf16_t* __restrict__ W2t,
                        const float* __restrict__ b2, const int* __restrict__ cnt,
                        const int* __restrict__ offs, const float* __restrict__ egate,
                        float* __restrict__ y) {
  const int wk = (blockIdx.x & 7) * 88 + (blockIdx.x >> 3);
  const int rt = wk % 22;
  const int g  = wk / 22;
  const int e  = g >> 2, nt = g & 3;
  const int count = cnt[e];
  if (rt * 192 >= count) return;

  __shared__ __align__(16) char smem[114688];

  const int tid = threadIdx.x, lane = tid & 63, wid = tid >> 6;
  const int wm = wid >> 2, wn = wid & 3;
  const int fr = lane & 15, lh = lane >> 4;
  const int hbase = offs[e];

  unsigned offA[2][2], offB[2][2];
#pragma unroll
  for (int j = 0; j < 2; ++j) {
    int q = j * 512 + tid;
    int r = q >> 3, sfg = (q & 7) ^ (r & 7);
#pragma unroll
    for (int h = 0; h < 2; ++h) {
      int ar = r < 96 ? r : 95;
      int gr = rt * 192 + h * 96 + ar;
      if (gr > count - 1) gr = count - 1;
      offA[h][j] = (unsigned)(((hbase + gr) * HID + sfg * 8) * 2);
      int brow = nt * 256 + h * 128 + r;
      offB[h][j] = (unsigned)(((e * OUTD + brow) * HID + sfg * 8) * 2);
    }
  }
  unsigned rdA[3][2], rdB[2][2];
#pragma unroll
  for (int i = 0; i < 3; ++i) {
    int r = wm * 48 + i * 16 + fr;
#pragma unroll
    for (int kk = 0; kk < 2; ++kk)
      rdA[i][kk] = (unsigned)(r * 128 + (((kk * 4 + lh) ^ (r & 7)) * 16));
  }
#pragma unroll
  for (int j = 0; j < 2; ++j) {
    int r = wn * 32 + j * 16 + fr;
#pragma unroll
    for (int kk = 0; kk < 2; ++kk)
      rdB[j][kk] = (unsigned)(r * 128 + (((kk * 4 + lh) ^ (r & 7)) * 16));
  }

  const char* Abase = (const char*)hbuf;
  const char* Bbase = (const char*)W2t;

  f32x4 acc[6][4];
#pragma unroll
  for (int i = 0; i < 6; ++i)
#pragma unroll
    for (int j = 0; j < 4; ++j) acc[i][j] = (f32x4){0.f, 0.f, 0.f, 0.f};

  const int NT = HID / 64;  // 32
  STAGE_A(0, 0); STAGE_B(0, 0); STAGE_A(0, 1); STAGE_B(0, 1);
  STAGE_A(1, 0); STAGE_B(1, 0);
  VMW_RING();
  BARRIER();

  for (int t = 0; t < NT; ++t) KTILE(t, NT);

#pragma unroll
  for (int mi = 0; mi < 6; ++mi) {
#pragma unroll
    for (int rr = 0; rr < 4; ++rr) {
      int rowp = rt * 192 + (mi / 3) * 96 + wm * 48 + (mi % 3) * 16 + lh * 4 + rr;
      if (rowp < count) {
        float gate = egate[e * T_TOK + rowp];
        size_t yrow = (size_t)(hbase + rowp) * OUTD;
#pragma unroll
        for (int nj = 0; nj < 4; ++nj) {
          int col = nt * 256 + (nj >> 1) * 128 + wn * 32 + (nj & 1) * 16 + fr;
          y[yrow + col] = gate * (acc[mi][nj][rr] + b2[e * OUTD + col]);
        }
      }
    }
  }
}

// ---------------- combine: out[t] = y[slot0] + y[slot1] ---------------------
__global__ void k_combine(const float* __restrict__ y, const int* __restrict__ offs,
                          const int* __restrict__ tokrec, float* __restrict__ out) {
  int t = blockIdx.x;
  int r0 = tokrec[2 * t], r1 = tokrec[2 * t + 1];
  int s0 = offs[r0 >> 16] + (r0 & 0xffff);
  int s1 = offs[r1 >> 16] + (r1 & 0xffff);
  const float4* ya = (const float4*)(y + (size_t)s0 * OUTD);
  const float4* yb = (const float4*)(y + (size_t)s1 * OUTD);
  float4* o = (float4*)(out + (size_t)t * OUTD);
  int i = threadIdx.x;
  float4 a = ya[i], b = yb[i];
  o[i] = make_float4(a.x + b.x, a.y + b.y, a.z + b.z, a.w + b.w);
}

// ---------------------------------------------------------------------------
extern "C" void kernel_launch(void* const* d_in, const int* in_sizes, int n_in,
                              void* d_out, int out_size, void* d_ws, size_t ws_size,
                              hipStream_t stream) {
  const float* x  = (const float*)d_in[0];
  const float* Wg = (const float*)d_in[1];
  const float* bg = (const float*)d_in[2];
  const float* W1 = (const float*)d_in[3];
  const float* b1 = (const float*)d_in[4];
  const float* W2 = (const float*)d_in[5];
  const float* b2 = (const float*)d_in[6];
  float* out = (float*)d_out;

  char* ws = (char*)d_ws;
  int*    cnt    = (int*)(ws);
  int*    offs   = (int*)(ws + 1024);
  int*    tokrec = (int*)(ws + 4096);                       // 32 KB
  int*    einfo  = (int*)(ws + 36864);                      // 16 KB
  float2* gpair  = (float2*)(ws + 53248);                   // 32 KB
  int*    elist  = (int*)(ws + 131072);                     // 128 KB
  float*  egate  = (float*)(ws + 262144);                   // 128 KB
  bf16_t* W1t    = (bf16_t*)(ws + (1u << 20));              // 32 MB
  float*  y      = (float*)(ws + (1u << 20));               // aliases W1t (dead by gemm2)
  bf16_t* W2t    = (bf16_t*)(ws + (1u << 20) + (32u << 20));// 32 MB
  bf16_t* xb     = (bf16_t*)(ws + (1u << 20) + (64u << 20));// 8 MB
  bf16_t* hbuf   = (bf16_t*)(ws + (1u << 20) + (72u << 20));// 32 MB

  k_front<<<NB_GATE + NB_TR1 + NB_TR2, 256, 0, stream>>>(
      x, Wg, bg, einfo, gpair, xb, W1, W1t, W2, W2t);
  k_bin<<<1, 512, 0, stream>>>(einfo, gpair, cnt, offs, elist, egate, tokrec);

  k_gemm1<<<8 * 176, 512, 0, stream>>>(xb, W1t, b1, cnt, offs, elist, hbuf);
  k_gemm2<<<8 * 88, 512, 0, stream>>>(hbuf, W2t, b2, cnt, offs, egate, y);
  k_combine<<<T_TOK, 256, 0, stream>>>(y, offs, tokrec, out);
}